// Round 14
// baseline (214.704 us; speedup 1.0000x reference)
//
#include <hip/hip_runtime.h>
#include <hip/hip_bf16.h>
#include <cstddef>

#define BATCH 16
#define CC 128
#define NN 16384
#define GROUPS 32
#define EPSV 1e-5f

// workspace float offsets
#define OFF_BEFF  1024       // 4096
#define OFF_CB    70656      // 2048
#define OFF_WH    334848     // 524288 ushorts (W_eff hi frags)
#define OFF_AH    596992     // 131072 fl (A_b hi frags)
#define OFF_AL    728064     // 131072 fl (A_b lo frags)
#define OFF_PART  859136     // 1024*4224 fl = 4325376
#define OFF_XT    5184512    // xt hi-only: 16*16384*128 shorts = 16777216 fl
#define PART_STRIDE 4224

typedef __attribute__((ext_vector_type(8))) short bf8;
typedef __attribute__((ext_vector_type(4))) float f4;
#define MFMA16(a,b,c) __builtin_amdgcn_mfma_f32_16x16x32_bf16(a,b,c,0,0,0)

__device__ inline unsigned short bf16_rtn(float f) {
    unsigned u = __builtin_bit_cast(unsigned, f);
    unsigned r = (u + 0x7FFFu + ((u >> 16) & 1u)) >> 16;
    return (unsigned short)r;
}
__device__ inline float bf16_f(unsigned short h) {
    unsigned u = ((unsigned)h) << 16;
    return __builtin_bit_cast(float, u);
}
// HW packed f32->bf16 (RNE); dst[15:0]=bf16(a), dst[31:16]=bf16(b)
__device__ inline unsigned cvtpk_bf16(float a, float b) {
    unsigned r;
    asm("v_cvt_pk_bf16_f32 %0, %1, %2" : "=v"(r) : "v"(a), "v"(b));
    return r;
}

// ---------------- K1a: transpose to [px][c] bf16-hi + fused GN partial stats ----------------
__global__ __launch_bounds__(256) void k1a_fused(const float* __restrict__ src,
        unsigned short* __restrict__ xt, float* __restrict__ gp) {
    int b = blockIdx.y; int p0 = blockIdx.x * 128; int t = threadIdx.x;
    __shared__ unsigned short lh[128 * 136];
    int p = t & 127, chalf = t >> 7;
    const float* sp = src + (size_t)b * CC * NN + p0 + p;
    #pragma unroll 8
    for (int i = 0; i < 64; ++i) {
        int c = i * 2 + chalf;
        float v = sp[(size_t)c * NN];
        lh[p * 136 + c] = bf16_rtn(v);
    }
    __syncthreads();
    // fused stats from bf16(x): thread covers group g = t>>3, 16 px x 4 ch
    {
        int g = t >> 3, i8 = t & 7;
        float s = 0.f, sq = 0.f;
        for (int pp = i8 * 16; pp < i8 * 16 + 16; ++pp) {
            #pragma unroll
            for (int cc = 0; cc < 4; ++cc) {
                float v = bf16_f(lh[pp * 136 + g * 4 + cc]);
                s += v; sq += v * v;
            }
        }
        __shared__ float rs[256], rq[256];
        rs[t] = s; rq[t] = sq;
        __syncthreads();
        if (t < 32) {
            float a = 0.f, bq = 0.f;
            #pragma unroll
            for (int k = 0; k < 8; ++k) { a += rs[t * 8 + k]; bq += rq[t * 8 + k]; }
            float* d = gp + ((size_t)(b * 128 + blockIdx.x) * 32 + t) * 2;
            d[0] = a; d[1] = bq;
        }
    }
    // transpose write (hi only)
    int pr = t >> 4, c8 = (t & 15) * 8;
    #pragma unroll
    for (int j = 0; j < 8; ++j) {
        int p2 = j * 16 + pr;
        bf8 vh = *(const bf8*)&lh[p2 * 136 + c8];
        *(bf8*)&xt[((size_t)b * NN + p0 + p2) * 128 + c8] = vh;
    }
}

// ---------------- K12: GN stats reduce + effective kv weights (fused k1b+k2) ----------------
__global__ void k12_weff(const float* __restrict__ gp,
                         const float* __restrict__ kv_w, const float* __restrict__ kv_b,
                         const float* __restrict__ gn_scale, const float* __restrict__ gn_bias,
                         float* __restrict__ wsf, unsigned short* __restrict__ wh) {
    int b = blockIdx.x; int t = threadIdx.x;
    __shared__ float mu_s[32], rs_s[32];
    {   // k1b: reduce group partials
        int g = t & 31, sl = t >> 5;
        float s = 0.f, sq = 0.f;
        for (int j = sl; j < 128; j += 8) {
            const float* p = gp + ((size_t)(b * 128 + j) * 32 + g) * 2;
            s += p[0]; sq += p[1];
        }
        __shared__ float rs[256], rq[256];
        rs[t] = s; rq[t] = sq; __syncthreads();
        if (t < 32) {
            #pragma unroll
            for (int k = 1; k < 8; ++k) { s += rs[t + 32 * k]; sq += rq[t + 32 * k]; }
            float mean = s * (1.f / 65536.f);
            float var  = sq * (1.f / 65536.f) - mean * mean;
            mu_s[t] = mean;
            rs_s[t] = rsqrtf(var + EPSV);
        }
        __syncthreads();
    }
    // k2: per-thread output o = t
    int o = t;
    float w[128]; float bacc = 0.f;
    #pragma unroll
    for (int c = 0; c < 128; ++c) {
        int g = c >> 2;
        float sc = gn_scale[c] * rs_s[g];
        float kw = kv_w[o * 128 + c];
        w[c] = kw * sc;
        bacc += kw * (gn_bias[c] - mu_s[g] * sc);
    }
    wsf[OFF_BEFF + b * 256 + o] = kv_b[o] + bacc;
    int h  = (o & 127) >> 5;
    int ct = ((o >> 4) & 1) + ((o >= 128) ? 2 : 0);
    int i  = o & 15;
    #pragma unroll
    for (int ks = 0; ks < 4; ++ks)
      #pragma unroll
      for (int eq = 0; eq < 4; ++eq) {
        bf8 pk;
        #pragma unroll
        for (int e = 0; e < 8; ++e) pk[e] = (short)bf16_rtn(w[ks*32 + eq*8 + e]);
        int lane = i + 16 * eq;
        size_t fo = ((((size_t)b * 4 + h) * 4 + ct) * 4 + ks) * 512 + (size_t)lane * 8;
        *(bf8*)&wh[fo] = pk;
      }
}

// ---------------- K3: MFMA kv-proj + streaming softmax-attention ----------------
// 2-ptgroup register prefetch pipeline
__global__ __launch_bounds__(256) void k3_attn(
    const unsigned short* __restrict__ xt,
    const unsigned short* __restrict__ wh, const float* __restrict__ wsf,
    float* __restrict__ part)
{
    int b = blockIdx.y, chunk = blockIdx.x;        // 64 chunks x 256 px
    int t = threadIdx.x, h = t >> 6, l = t & 63;
    int l15 = l & 15, lq = l >> 4;

    __shared__ unsigned short lds[4][2][32 * 64];  // [wave][ek|v][32 rows][64 px]

    bf8 W[4][4];                                    // [ct][ks], hi only
    #pragma unroll
    for (int ct = 0; ct < 4; ++ct)
      #pragma unroll
      for (int ks = 0; ks < 4; ++ks)
        W[ct][ks] = ((const bf8*)wh)[((((size_t)b*4 + h)*4 + ct)*4 + ks)*64 + l];

    float bk[4];
    #pragma unroll
    for (int ct = 0; ct < 4; ++ct) {
        int o = (ct < 2) ? (32*h + 16*ct + l15) : (128 + 32*h + 16*(ct-2) + l15);
        bk[ct] = wsf[OFF_BEFF + b * 256 + o];
    }

    bf8 ones;
    #pragma unroll
    for (int j = 0; j < 8; ++j) ones[j] = (short)0x3F80;

    f4 ctx[2][2]; f4 zac[2];
    #pragma unroll
    for (int i = 0; i < 2; ++i) {
        zac[i] = (f4){0,0,0,0};
        #pragma unroll
        for (int j = 0; j < 2; ++j) ctx[i][j] = (f4){0,0,0,0};
    }

    int pbase = chunk * 256;
    const unsigned short* xbase = xt + ((size_t)b * NN + pbase + l15) * 128 + lq * 8;
    #define FRAG(fp, ks) (*(const bf8*)(xbase + (size_t)(fp) * 2048 + (ks) * 32))

    bf8 pre[2][4];
    #pragma unroll
    for (int i = 0; i < 2; ++i)
      #pragma unroll
      for (int ks = 0; ks < 4; ++ks) pre[i][ks] = FRAG(i, ks);

    for (int tile = 0; tile < 4; ++tile) {
        #pragma unroll
        for (int half = 0; half < 2; ++half) {
            int nfp = tile * 4 + half * 2 + 2;
            int cfp = (nfp < 16) ? nfp : 0;
            bf8 nxt[2][4];
            #pragma unroll
            for (int i = 0; i < 2; ++i)
              #pragma unroll
              for (int ks = 0; ks < 4; ++ks) nxt[i][ks] = FRAG(cfp + i, ks);
            #pragma unroll
            for (int i = 0; i < 2; ++i) {
                int pt = half * 2 + i;
                f4 a4[4];
                #pragma unroll
                for (int ct = 0; ct < 4; ++ct) a4[ct] = (f4){0,0,0,0};
                #pragma unroll
                for (int ks = 0; ks < 4; ++ks) {
                    #pragma unroll
                    for (int ct = 0; ct < 4; ++ct)
                        a4[ct] = MFMA16(pre[i][ks], W[ct][ks], a4[ct]);
                }
                int p = pt * 16 + lq * 4;          // 4 consecutive px
                #pragma unroll
                for (int ct = 0; ct < 4; ++ct) {
                    int row = (ct & 1) * 16 + l15;
                    int sel = ct >> 1;             // 0 = EK, 1 = V
                    float v0 = a4[ct][0] + bk[ct];
                    float v1 = a4[ct][1] + bk[ct];
                    float v2 = a4[ct][2] + bk[ct];
                    float v3 = a4[ct][3] + bk[ct];
                    if (sel == 0) {
                        v0 = __expf(v0); v1 = __expf(v1);
                        v2 = __expf(v2); v3 = __expf(v3);
                    }
                    unsigned lo32 = cvtpk_bf16(v0, v1);
                    unsigned hi32 = cvtpk_bf16(v2, v3);
                    unsigned byte = ((unsigned)(row * 128 + p * 2)) ^ (((unsigned)(row & 7)) << 4);
                    *(uint2*)((char*)&lds[h][sel][0] + byte) = make_uint2(lo32, hi32);
                }
            }
            #pragma unroll
            for (int i = 0; i < 2; ++i)
              #pragma unroll
              for (int ks = 0; ks < 4; ++ks) pre[i][ks] = nxt[i][ks];
        }
        // PV + Z (wave-local; compiler inserts lgkmcnt)
        #pragma unroll
        for (int ks2 = 0; ks2 < 2; ++ks2) {
            int p8 = ks2 * 32 + lq * 8;
            bf8 ek[2], vv[2];
            #pragma unroll
            for (int dt = 0; dt < 2; ++dt) {
                int row = dt * 16 + l15;
                unsigned byte = ((unsigned)(row * 128 + p8 * 2)) ^ (((unsigned)(row & 7)) << 4);
                ek[dt] = *(const bf8*)((char*)&lds[h][0][0] + byte);
                vv[dt] = *(const bf8*)((char*)&lds[h][1][0] + byte);
            }
            #pragma unroll
            for (int dt = 0; dt < 2; ++dt) {
                #pragma unroll
                for (int et = 0; et < 2; ++et)
                    ctx[dt][et] = MFMA16(ek[dt], vv[et], ctx[dt][et]);
                zac[dt] = MFMA16(ek[dt], ones, zac[dt]);
            }
        }
    }
    #undef FRAG
    // partial write
    float* pb = part + (size_t)(b * 64 + chunk) * PART_STRIDE;
    #pragma unroll
    for (int dt = 0; dt < 2; ++dt) {
        #pragma unroll
        for (int et = 0; et < 2; ++et)
            #pragma unroll
            for (int j = 0; j < 4; ++j) {
                int d = 32*h + dt*16 + lq*4 + j;
                int e = et*16 + l15;
                pb[d * 32 + e] = ctx[dt][et][j];
            }
        if (l15 == 0)
            #pragma unroll
            for (int j = 0; j < 4; ++j)
                pb[4096 + 32*h + dt*16 + lq*4 + j] = zac[dt][j];
    }
}

// ---------------- K45: partial reduce -> ctx (LDS) -> A_b build + frag-pack (fused k4+k5) ----------------
// grid (4, BATCH): each block redundantly reduces the full batch partials
// (L2/L3-resident, just written by k3), then handles 2 oh-chunks of k5.
__global__ __launch_bounds__(256) void k45_fused(const float* __restrict__ part,
                          const float* __restrict__ out_w, const float* __restrict__ q_w,
                          const float* __restrict__ q_b, const float* __restrict__ out_b,
                          float* __restrict__ wsf,
                          unsigned short* __restrict__ ahp, unsigned short* __restrict__ alp) {
    int b = blockIdx.y;
    int tid = threadIdx.x;
    __shared__ float ctx_p[128 * 33];
    __shared__ float T_s[16 * 132];
    __shared__ float zs[128];
    // phase 1: full-batch reduce (hd = tid>>1, e0 = (tid&1)*16)
    {
        int hd = tid >> 1, e0 = (tid & 1) * 16;
        float s[16];
        #pragma unroll
        for (int j = 0; j < 16; ++j) s[j] = 0.f;
        float z = 0.f;
        for (int i = 0; i < 64; ++i) {
            const float* pb = part + (size_t)(b * 64 + i) * PART_STRIDE;
            #pragma unroll
            for (int j4 = 0; j4 < 4; ++j4) {
                float4 v = *(const float4*)&pb[hd * 32 + e0 + j4 * 4];
                s[j4*4+0] += v.x; s[j4*4+1] += v.y; s[j4*4+2] += v.z; s[j4*4+3] += v.w;
            }
            if ((tid & 1) == 0) z += pb[4096 + hd];
        }
        if ((tid & 1) == 0) zs[hd] = z;
        __syncthreads();
        float zi = 1.f / zs[hd];
        #pragma unroll
        for (int j = 0; j < 16; ++j) ctx_p[hd * 33 + e0 + j] = s[j] * zi;
    }
    __syncthreads();
    // phase 2: two oh-chunks of the A_b build
    int ol = tid >> 4;                  // 0..15
    int jb = tid & 15;                  // 0..15
    int j0 = jb * 8;
    int h = j0 >> 5;
    for (int c2 = 0; c2 < 2; ++c2) {
        int oh = blockIdx.x * 32 + c2 * 16;
        int o = oh + ol;
        {   // phase A: T[o][j0..j0+8)
            float ow[32];
            #pragma unroll
            for (int e4 = 0; e4 < 8; ++e4) {
                float4 v = *(const float4*)&out_w[o * 128 + h * 32 + e4 * 4];
                ow[e4*4+0]=v.x; ow[e4*4+1]=v.y; ow[e4*4+2]=v.z; ow[e4*4+3]=v.w;
            }
            #pragma unroll
            for (int dd = 0; dd < 8; ++dd) {
                int r = h * 32 + (j0 & 31) + dd;
                const float* cp = &ctx_p[r * 33];
                float a0 = 0.f, a1 = 0.f, a2 = 0.f, a3 = 0.f;
                #pragma unroll
                for (int e = 0; e < 32; e += 4) {
                    a0 += ow[e+0] * cp[e+0];
                    a1 += ow[e+1] * cp[e+1];
                    a2 += ow[e+2] * cp[e+2];
                    a3 += ow[e+3] * cp[e+3];
                }
                T_s[ol * 132 + j0 + dd] = (a0 + a1) + (a2 + a3);
            }
        }
        __syncthreads();
        {   // phase B: A[o][ci0..ci0+8) + frag-pack
            int ci0 = jb * 8;
            float a[8];
            #pragma unroll
            for (int i = 0; i < 8; ++i) a[i] = 0.f;
            for (int j = 0; j < 128; ++j) {
                float tv = T_s[ol * 132 + j];
                float4 v0 = *(const float4*)&q_w[j * 128 + ci0];
                float4 v1 = *(const float4*)&q_w[j * 128 + ci0 + 4];
                a[0] += tv*v0.x; a[1] += tv*v0.y; a[2] += tv*v0.z; a[3] += tv*v0.w;
                a[4] += tv*v1.x; a[5] += tv*v1.y; a[6] += tv*v1.z; a[7] += tv*v1.w;
            }
            int ks = ci0 >> 5;
            int eq = (ci0 >> 3) & 3;
            int lane = (o & 15) + 16 * eq;
            bf8 ph, pl;
            #pragma unroll
            for (int e = 0; e < 8; ++e) {
                unsigned short hh = bf16_rtn(a[e]);
                ph[e] = (short)hh;
                pl[e] = (short)bf16_rtn(a[e] - bf16_f(hh));
            }
            size_t fo = ((((size_t)b * 8 + (o >> 4)) * 4 + ks) * 64 + lane) * 8;
            *(bf8*)&ahp[fo] = ph;
            *(bf8*)&alp[fo] = pl;
            if (jb == 0) {
                float cb = 0.f;
                for (int j = 0; j < 128; ++j) cb += T_s[ol * 132 + j] * q_b[j];
                wsf[OFF_CB + b * 128 + o] = cb + out_b[o];
            }
        }
        __syncthreads();
    }
}

// ---------------- K6 (MFMA): y = A_b . cond + c_b ----------------
// producer/consumer with T14 async-stage
__global__ __launch_bounds__(256) void k6_mfma(
    const float* __restrict__ cond,
    const unsigned short* __restrict__ ahp, const unsigned short* __restrict__ alp,
    const float* __restrict__ wsf, float* __restrict__ y)
{
    int b = blockIdx.y, chunk = blockIdx.x;        // 64 chunks x 256 px
    int t = threadIdx.x, w = t >> 6, l = t & 63, l15 = l & 15, lq = l >> 4;

    __shared__ __align__(16) unsigned short bfr[4][4][2][512];  // [pt][ks][hi/lo][lane*8]

    bf8 Ah[2][4], Al[2][4];
    #pragma unroll
    for (int r = 0; r < 2; ++r)
      #pragma unroll
      for (int ks = 0; ks < 4; ++ks) {
        size_t idx = (((size_t)b * 8 + (2*w + r)) * 4 + ks) * 64 + l;
        Ah[r][ks] = ((const bf8*)ahp)[idx];
        Al[r][ks] = ((const bf8*)alp)[idx];
      }
    float cbl[2][4];
    #pragma unroll
    for (int r = 0; r < 2; ++r)
      #pragma unroll
      for (int j = 0; j < 4; ++j)
        cbl[r][j] = wsf[OFF_CB + b*128 + (2*w + r)*16 + lq*4 + j];

    int pbase = chunk * 256;
    const float* cb0 = cond + (size_t)b * 128 * NN + pbase + w*16 + l15;

    float v[4][8];
    #pragma unroll
    for (int ks = 0; ks < 4; ++ks)
      #pragma unroll
      for (int j = 0; j < 8; ++j)
        v[ks][j] = cb0[(size_t)(ks*32 + lq*8 + j) * NN];

    for (int tile = 0; tile < 4; ++tile) {
        if (tile > 0) __syncthreads();
        #pragma unroll
        for (int ks = 0; ks < 4; ++ks) {
            union { unsigned u[4]; bf8 s; } uh, ul;
            #pragma unroll
            for (int q = 0; q < 4; ++q) {
                unsigned hp = cvtpk_bf16(v[ks][2*q], v[ks][2*q+1]);
                uh.u[q] = hp;
                float f0 = __builtin_bit_cast(float, hp << 16);
                float f1 = __builtin_bit_cast(float, hp & 0xFFFF0000u);
                ul.u[q] = cvtpk_bf16(v[ks][2*q] - f0, v[ks][2*q+1] - f1);
            }
            *(bf8*)&bfr[w][ks][0][l * 8] = uh.s;
            *(bf8*)&bfr[w][ks][1][l * 8] = ul.s;
        }
        __syncthreads();
        if (tile < 3) {
            const float* cp = cb0 + (tile + 1) * 64;
            #pragma unroll
            for (int ks = 0; ks < 4; ++ks)
              #pragma unroll
              for (int j = 0; j < 8; ++j)
                v[ks][j] = cp[(size_t)(ks*32 + lq*8 + j) * NN];
        }
        int tp = pbase + tile * 64;
        f4 acc[2][4];
        #pragma unroll
        for (int r = 0; r < 2; ++r)
          #pragma unroll
          for (int pt = 0; pt < 4; ++pt) acc[r][pt] = (f4){0,0,0,0};
        #pragma unroll
        for (int pt = 0; pt < 4; ++pt) {
            #pragma unroll
            for (int ks = 0; ks < 4; ++ks) {
                bf8 bh = *(const bf8*)&bfr[pt][ks][0][l * 8];
                bf8 bl = *(const bf8*)&bfr[pt][ks][1][l * 8];
                #pragma unroll
                for (int r = 0; r < 2; ++r) {
                    acc[r][pt] = MFMA16(Ah[r][ks], bh, acc[r][pt]);
                    acc[r][pt] = MFMA16(Al[r][ks], bh, acc[r][pt]);
                    acc[r][pt] = MFMA16(Ah[r][ks], bl, acc[r][pt]);
                }
            }
        }
        #pragma unroll
        for (int r = 0; r < 2; ++r)
          #pragma unroll
          for (int pt = 0; pt < 4; ++pt)
            #pragma unroll
            for (int j = 0; j < 4; ++j) {
                int o = (2*w + r)*16 + lq*4 + j;
                int p = tp + pt*16 + l15;
                y[((size_t)b*128 + o)*NN + p] = acc[r][pt][j] + cbl[r][j];
            }
    }
}

extern "C" void kernel_launch(void* const* d_in, const int* in_sizes, int n_in,
                              void* d_out, int out_size, void* d_ws, size_t ws_size,
                              hipStream_t stream) {
    const float* x        = (const float*)d_in[0];
    const float* cond     = (const float*)d_in[1];
    const float* gn_scale = (const float*)d_in[2];
    const float* gn_bias  = (const float*)d_in[3];
    const float* kv_w     = (const float*)d_in[4];
    const float* kv_b     = (const float*)d_in[5];
    const float* q_w      = (const float*)d_in[6];
    const float* q_b      = (const float*)d_in[7];
    const float* out_w    = (const float*)d_in[8];
    const float* out_b    = (const float*)d_in[9];
    float* y   = (float*)d_out;
    float* wsf = (float*)d_ws;

    unsigned short* WH = (unsigned short*)(wsf + OFF_WH);
    unsigned short* AH = (unsigned short*)(wsf + OFF_AH);
    unsigned short* AL = (unsigned short*)(wsf + OFF_AL);
    float* part = wsf + OFF_PART;

    bool big = ws_size >= (size_t)(OFF_XT + 16777216) * sizeof(float);

    unsigned short* XT;
    if (big) {
        XT = (unsigned short*)(wsf + OFF_XT);
    } else {
        XT = (unsigned short*)y;           // consumed by k3 before k6 writes y
    }

    k1a_fused<<<dim3(128, BATCH), 256, 0, stream>>>(x, XT, part);
    k12_weff<<<BATCH, 256, 0, stream>>>(part, kv_w, kv_b, gn_scale, gn_bias, wsf, WH);
    k3_attn<<<dim3(64, BATCH), 256, 0, stream>>>(XT, WH, wsf, part);
    k45_fused<<<dim3(4, BATCH), 256, 0, stream>>>(part, out_w, q_w, q_b, out_b, wsf, AH, AL);
    k6_mfma<<<dim3(64, BATCH), 256, 0, stream>>>(cond, AH, AL, wsf, y);
}

// Round 15
// 195.359 us; speedup vs baseline: 1.0990x; 1.0990x over previous
//
#include <hip/hip_runtime.h>
#include <hip/hip_bf16.h>
#include <cstddef>

#define BATCH 16
#define CC 128
#define NN 16384
#define GROUPS 32
#define EPSV 1e-5f

// workspace float offsets
#define OFF_MU    0          // 512
#define OFF_RSTD  512        // 512
#define OFF_BEFF  1024       // 4096
#define OFF_CTX   5120       // 65536
#define OFF_CB    70656      // 2048
#define OFF_WH    334848     // 524288 ushorts (W_eff hi frags)
#define OFF_AH    596992     // 131072 fl (A_b hi frags)
#define OFF_AL    728064     // 131072 fl (A_b lo frags)
#define OFF_PART  859136     // 1024*4224 fl = 4325376
#define OFF_XT    5184512    // xt hi-only: 16*16384*128 shorts = 16777216 fl
#define PART_STRIDE 4224

typedef __attribute__((ext_vector_type(8))) short bf8;
typedef __attribute__((ext_vector_type(4))) float f4;
#define MFMA16(a,b,c) __builtin_amdgcn_mfma_f32_16x16x32_bf16(a,b,c,0,0,0)

__device__ inline unsigned short bf16_rtn(float f) {
    unsigned u = __builtin_bit_cast(unsigned, f);
    unsigned r = (u + 0x7FFFu + ((u >> 16) & 1u)) >> 16;
    return (unsigned short)r;
}
__device__ inline float bf16_f(unsigned short h) {
    unsigned u = ((unsigned)h) << 16;
    return __builtin_bit_cast(float, u);
}
// HW packed f32->bf16 (RNE); dst[15:0]=bf16(a), dst[31:16]=bf16(b)
__device__ inline unsigned cvtpk_bf16(float a, float b) {
    unsigned r;
    asm("v_cvt_pk_bf16_f32 %0, %1, %2" : "=v"(r) : "v"(a), "v"(b));
    return r;
}

// ---------------- K1a: transpose to [px][c] bf16-hi + fused GN partial stats ----------------
__global__ __launch_bounds__(256) void k1a_fused(const float* __restrict__ src,
        unsigned short* __restrict__ xt, float* __restrict__ gp) {
    int b = blockIdx.y; int p0 = blockIdx.x * 128; int t = threadIdx.x;
    __shared__ unsigned short lh[128 * 136];
    int p = t & 127, chalf = t >> 7;
    const float* sp = src + (size_t)b * CC * NN + p0 + p;
    #pragma unroll 8
    for (int i = 0; i < 64; ++i) {
        int c = i * 2 + chalf;
        float v = sp[(size_t)c * NN];
        lh[p * 136 + c] = bf16_rtn(v);
    }
    __syncthreads();
    // fused stats from bf16(x): thread covers group g = t>>3, 16 px x 4 ch
    {
        int g = t >> 3, i8 = t & 7;
        float s = 0.f, sq = 0.f;
        for (int pp = i8 * 16; pp < i8 * 16 + 16; ++pp) {
            #pragma unroll
            for (int cc = 0; cc < 4; ++cc) {
                float v = bf16_f(lh[pp * 136 + g * 4 + cc]);
                s += v; sq += v * v;
            }
        }
        __shared__ float rs[256], rq[256];
        rs[t] = s; rq[t] = sq;
        __syncthreads();
        if (t < 32) {
            float a = 0.f, bq = 0.f;
            #pragma unroll
            for (int k = 0; k < 8; ++k) { a += rs[t * 8 + k]; bq += rq[t * 8 + k]; }
            float* d = gp + ((size_t)(b * 128 + blockIdx.x) * 32 + t) * 2;
            d[0] = a; d[1] = bq;
        }
    }
    // transpose write (hi only)
    int pr = t >> 4, c8 = (t & 15) * 8;
    #pragma unroll
    for (int j = 0; j < 8; ++j) {
        int p2 = j * 16 + pr;
        bf8 vh = *(const bf8*)&lh[p2 * 136 + c8];
        *(bf8*)&xt[((size_t)b * NN + p0 + p2) * 128 + c8] = vh;
    }
}

// ---------------- K1b: reduce group partials -> mu/rstd ----------------
__global__ void k1b_stats(const float* __restrict__ gp, float* __restrict__ wsf) {
    int b = blockIdx.x; int t = threadIdx.x;
    int g = t & 31, sl = t >> 5;
    float s = 0.f, sq = 0.f;
    for (int j = sl; j < 128; j += 8) {
        const float* p = gp + ((size_t)(b * 128 + j) * 32 + g) * 2;
        s += p[0]; sq += p[1];
    }
    __shared__ float rs[256], rq[256];
    rs[t] = s; rq[t] = sq; __syncthreads();
    if (t < 32) {
        #pragma unroll
        for (int k = 1; k < 8; ++k) { s += rs[t + 32 * k]; sq += rq[t + 32 * k]; }
        float mean = s * (1.f / 65536.f);
        float var  = sq * (1.f / 65536.f) - mean * mean;
        wsf[OFF_MU + b * 32 + t]   = mean;
        wsf[OFF_RSTD + b * 32 + t] = rsqrtf(var + EPSV);
    }
}

// ---------------- K2 v2: effective kv weights, coalesced via LDS (128 blocks) ----------------
__global__ __launch_bounds__(256) void k2_weff(const float* __restrict__ kv_w,
                        const float* __restrict__ kv_b,
                        const float* __restrict__ gn_scale, const float* __restrict__ gn_bias,
                        float* __restrict__ wsf, unsigned short* __restrict__ wh) {
    int b = blockIdx.y;
    int o0 = blockIdx.x * 32;           // 8 o-chunks x 32 outputs
    int t = threadIdx.x;
    __shared__ float wrow[32 * 128];    // 16 KB, kv_w rows o0..o0+32
    __shared__ float scl[128], sbm[128];// gamma*rstd ; gn_bias - mu*gamma*rstd
    __shared__ float bred[32][8];
    {   // coalesced stage: 4096 floats
        const float4* src = (const float4*)(kv_w + (size_t)o0 * 128);
        float4* dst = (float4*)wrow;
        #pragma unroll
        for (int i = 0; i < 4; ++i) dst[i * 256 + t] = src[i * 256 + t];
        if (t < 128) {
            int g = t >> 2;
            float r = wsf[OFF_RSTD + b * 32 + g];
            float m = wsf[OFF_MU + b * 32 + g];
            float sc = gn_scale[t] * r;
            scl[t] = sc;
            sbm[t] = gn_bias[t] - m * sc;
        }
    }
    __syncthreads();
    int ol = t >> 3;                    // 0..31
    int o  = o0 + ol;
    int q  = t & 7;                     // 2 frags: f = 2q, 2q+1
    // bias partial over c in [q*16, q*16+16)
    {
        float bacc = 0.f;
        const float* wr = &wrow[ol * 128 + q * 16];
        #pragma unroll
        for (int c = 0; c < 16; ++c) bacc += wr[c] * sbm[q * 16 + c];
        bred[ol][q] = bacc;
    }
    // pack 2 frags
    int h  = (o & 127) >> 5;
    int ct = ((o >> 4) & 1) + ((o >= 128) ? 2 : 0);
    #pragma unroll
    for (int f2 = 0; f2 < 2; ++f2) {
        int f = 2 * q + f2;
        int ks = f >> 2, eq = f & 3;
        int c0 = ks * 32 + eq * 8;
        bf8 pk;
        #pragma unroll
        for (int e = 0; e < 8; ++e)
            pk[e] = (short)bf16_rtn(wrow[ol * 128 + c0 + e] * scl[c0 + e]);
        int lane = (o & 15) + 16 * eq;
        size_t fo = ((((size_t)b * 4 + h) * 4 + ct) * 4 + ks) * 512 + (size_t)lane * 8;
        *(bf8*)&wh[fo] = pk;
    }
    __syncthreads();
    if (q == 0) {
        float bacc = 0.f;
        #pragma unroll
        for (int k = 0; k < 8; ++k) bacc += bred[ol][k];
        wsf[OFF_BEFF + b * 256 + o] = kv_b[o] + bacc;
    }
}

// ---------------- K3: MFMA kv-proj + streaming softmax-attention ----------------
// 1-group-deep register prefetch pipeline (lower VGPR -> more waves/SIMD)
__global__ __launch_bounds__(256) void k3_attn(
    const unsigned short* __restrict__ xt,
    const unsigned short* __restrict__ wh, const float* __restrict__ wsf,
    float* __restrict__ part)
{
    int b = blockIdx.y, chunk = blockIdx.x;        // 64 chunks x 256 px
    int t = threadIdx.x, h = t >> 6, l = t & 63;
    int l15 = l & 15, lq = l >> 4;

    __shared__ unsigned short lds[4][2][32 * 64];  // [wave][ek|v][32 rows][64 px]

    bf8 W[4][4];                                    // [ct][ks], hi only
    #pragma unroll
    for (int ct = 0; ct < 4; ++ct)
      #pragma unroll
      for (int ks = 0; ks < 4; ++ks)
        W[ct][ks] = ((const bf8*)wh)[((((size_t)b*4 + h)*4 + ct)*4 + ks)*64 + l];

    float bk[4];
    #pragma unroll
    for (int ct = 0; ct < 4; ++ct) {
        int o = (ct < 2) ? (32*h + 16*ct + l15) : (128 + 32*h + 16*(ct-2) + l15);
        bk[ct] = wsf[OFF_BEFF + b * 256 + o];
    }

    bf8 ones;
    #pragma unroll
    for (int j = 0; j < 8; ++j) ones[j] = (short)0x3F80;

    f4 ctx[2][2]; f4 zac[2];
    #pragma unroll
    for (int i = 0; i < 2; ++i) {
        zac[i] = (f4){0,0,0,0};
        #pragma unroll
        for (int j = 0; j < 2; ++j) ctx[i][j] = (f4){0,0,0,0};
    }

    int pbase = chunk * 256;
    const unsigned short* xbase = xt + ((size_t)b * NN + pbase + l15) * 128 + lq * 8;
    #define FRAG(fp, ks) (*(const bf8*)(xbase + (size_t)(fp) * 2048 + (ks) * 32))

    bf8 cur[4];
    #pragma unroll
    for (int ks = 0; ks < 4; ++ks) cur[ks] = FRAG(0, ks);

    for (int tile = 0; tile < 4; ++tile) {
        #pragma unroll
        for (int g = 0; g < 4; ++g) {
            // prefetch next pixel-group (clamped tail reload = harmless L2 hit)
            int nfp = tile * 4 + g + 1;
            int cfp = (nfp < 16) ? nfp : 0;
            bf8 nxt[4];
            #pragma unroll
            for (int ks = 0; ks < 4; ++ks) nxt[ks] = FRAG(cfp, ks);
            // proj + pack for current group (pt = g)
            f4 a4[4];
            #pragma unroll
            for (int ct = 0; ct < 4; ++ct) a4[ct] = (f4){0,0,0,0};
            #pragma unroll
            for (int ks = 0; ks < 4; ++ks) {
                #pragma unroll
                for (int ct = 0; ct < 4; ++ct)
                    a4[ct] = MFMA16(cur[ks], W[ct][ks], a4[ct]);
            }
            int p = g * 16 + lq * 4;               // 4 consecutive px
            #pragma unroll
            for (int ct = 0; ct < 4; ++ct) {
                int row = (ct & 1) * 16 + l15;
                int sel = ct >> 1;                 // 0 = EK, 1 = V
                float v0 = a4[ct][0] + bk[ct];
                float v1 = a4[ct][1] + bk[ct];
                float v2 = a4[ct][2] + bk[ct];
                float v3 = a4[ct][3] + bk[ct];
                if (sel == 0) {
                    v0 = __expf(v0); v1 = __expf(v1);
                    v2 = __expf(v2); v3 = __expf(v3);
                }
                unsigned lo32 = cvtpk_bf16(v0, v1);
                unsigned hi32 = cvtpk_bf16(v2, v3);
                unsigned byte = ((unsigned)(row * 128 + p * 2)) ^ (((unsigned)(row & 7)) << 4);
                *(uint2*)((char*)&lds[h][sel][0] + byte) = make_uint2(lo32, hi32);
            }
            // rotate
            #pragma unroll
            for (int ks = 0; ks < 4; ++ks) cur[ks] = nxt[ks];
        }
        // PV + Z (wave-local; compiler inserts lgkmcnt)
        #pragma unroll
        for (int ks2 = 0; ks2 < 2; ++ks2) {
            int p8 = ks2 * 32 + lq * 8;
            bf8 ek[2], vv[2];
            #pragma unroll
            for (int dt = 0; dt < 2; ++dt) {
                int row = dt * 16 + l15;
                unsigned byte = ((unsigned)(row * 128 + p8 * 2)) ^ (((unsigned)(row & 7)) << 4);
                ek[dt] = *(const bf8*)((char*)&lds[h][0][0] + byte);
                vv[dt] = *(const bf8*)((char*)&lds[h][1][0] + byte);
            }
            #pragma unroll
            for (int dt = 0; dt < 2; ++dt) {
                #pragma unroll
                for (int et = 0; et < 2; ++et)
                    ctx[dt][et] = MFMA16(ek[dt], vv[et], ctx[dt][et]);
                zac[dt] = MFMA16(ek[dt], ones, zac[dt]);
            }
        }
    }
    #undef FRAG
    // partial write
    float* pb = part + (size_t)(b * 64 + chunk) * PART_STRIDE;
    #pragma unroll
    for (int dt = 0; dt < 2; ++dt) {
        #pragma unroll
        for (int et = 0; et < 2; ++et)
            #pragma unroll
            for (int j = 0; j < 4; ++j) {
                int d = 32*h + dt*16 + lq*4 + j;
                int e = et*16 + l15;
                pb[d * 32 + e] = ctx[dt][et][j];
            }
        if (l15 == 0)
            #pragma unroll
            for (int j = 0; j < 4; ++j)
                pb[4096 + 32*h + dt*16 + lq*4 + j] = zac[dt][j];
    }
}

// ---------------- K4: reduce partials -> context = S/Z ----------------
__global__ __launch_bounds__(256) void k4_reduce(const float* __restrict__ part,
                                                 float* __restrict__ wsf, int nbpb) {
    int q = blockIdx.x, b = blockIdx.y;
    int tid = threadIdx.x;
    int hdl = tid >> 3;                 // 0..31
    int hd = q * 32 + hdl;
    int e0 = (tid & 7) * 4;
    float s[4] = {0.f, 0.f, 0.f, 0.f};
    float z = 0.f;
    for (int i = 0; i < nbpb; ++i) {
        const float* pb = part + (size_t)(b * nbpb + i) * PART_STRIDE;
        float4 v = *(const float4*)&pb[hd * 32 + e0];
        s[0] += v.x; s[1] += v.y; s[2] += v.z; s[3] += v.w;
        if ((tid & 7) == 0) z += pb[4096 + hd];
    }
    __shared__ float zs[32];
    if ((tid & 7) == 0) zs[hdl] = z;
    __syncthreads();
    float zi = 1.f / zs[hdl];
    float* cg = wsf + OFF_CTX + (size_t)b * 4096;
    #pragma unroll
    for (int j = 0; j < 4; ++j) cg[hd * 32 + e0 + j] = s[j] * zi;
}

// ---------------- K5: A_b = out_w . blockdiag(ctx^T) . q_w ; c_b ; frag-pack ----------------
__global__ __launch_bounds__(256) void k5_buildA(const float* __restrict__ out_w,
                          const float* __restrict__ q_w,
                          const float* __restrict__ q_b, const float* __restrict__ out_b,
                          float* __restrict__ wsf,
                          unsigned short* __restrict__ ahp, unsigned short* __restrict__ alp) {
    int b = blockIdx.y;
    int oh = blockIdx.x * 16;           // 8 o-chunks of 16 rows
    int tid = threadIdx.x;
    __shared__ float ctx_p[128 * 33];
    __shared__ float T_s[16 * 132];
    {
        const float* src = wsf + OFF_CTX + (size_t)b * 4096;
        for (int i = tid; i < 4096; i += 256)
            ctx_p[(i >> 5) * 33 + (i & 31)] = src[i];
    }
    __syncthreads();
    int ol = tid >> 4;                  // 0..15
    int o = oh + ol;
    int jb = tid & 15;                  // 0..15
    int j0 = jb * 8;
    int h = j0 >> 5;
    {
        float ow[32];
        #pragma unroll
        for (int e4 = 0; e4 < 8; ++e4) {
            float4 v = *(const float4*)&out_w[o * 128 + h * 32 + e4 * 4];
            ow[e4*4+0]=v.x; ow[e4*4+1]=v.y; ow[e4*4+2]=v.z; ow[e4*4+3]=v.w;
        }
        #pragma unroll
        for (int dd = 0; dd < 8; ++dd) {
            int r = h * 32 + (j0 & 31) + dd;
            const float* cp = &ctx_p[r * 33];
            float a0 = 0.f, a1 = 0.f, a2 = 0.f, a3 = 0.f;
            #pragma unroll
            for (int e = 0; e < 32; e += 4) {
                a0 += ow[e+0] * cp[e+0];
                a1 += ow[e+1] * cp[e+1];
                a2 += ow[e+2] * cp[e+2];
                a3 += ow[e+3] * cp[e+3];
            }
            T_s[ol * 132 + j0 + dd] = (a0 + a1) + (a2 + a3);
        }
    }
    __syncthreads();
    {
        int ci0 = jb * 8;
        float a[8];
        #pragma unroll
        for (int i = 0; i < 8; ++i) a[i] = 0.f;
        for (int j = 0; j < 128; ++j) {
            float tv = T_s[ol * 132 + j];
            float4 v0 = *(const float4*)&q_w[j * 128 + ci0];
            float4 v1 = *(const float4*)&q_w[j * 128 + ci0 + 4];
            a[0] += tv*v0.x; a[1] += tv*v0.y; a[2] += tv*v0.z; a[3] += tv*v0.w;
            a[4] += tv*v1.x; a[5] += tv*v1.y; a[6] += tv*v1.z; a[7] += tv*v1.w;
        }
        int ks = ci0 >> 5;
        int eq = (ci0 >> 3) & 3;
        int lane = (o & 15) + 16 * eq;
        bf8 ph, pl;
        #pragma unroll
        for (int e = 0; e < 8; ++e) {
            unsigned short hh = bf16_rtn(a[e]);
            ph[e] = (short)hh;
            pl[e] = (short)bf16_rtn(a[e] - bf16_f(hh));
        }
        size_t fo = ((((size_t)b * 8 + (o >> 4)) * 4 + ks) * 64 + lane) * 8;
        *(bf8*)&ahp[fo] = ph;
        *(bf8*)&alp[fo] = pl;
        if (jb == 0) {
            float cb = 0.f;
            for (int j = 0; j < 128; ++j) cb += T_s[ol * 132 + j] * q_b[j];
            wsf[OFF_CB + b * 128 + o] = cb + out_b[o];
        }
    }
}

// ---------------- K6 (MFMA): y = A_b . cond + c_b ----------------
// producer/consumer with T14 async-stage
__global__ __launch_bounds__(256) void k6_mfma(
    const float* __restrict__ cond,
    const unsigned short* __restrict__ ahp, const unsigned short* __restrict__ alp,
    const float* __restrict__ wsf, float* __restrict__ y)
{
    int b = blockIdx.y, chunk = blockIdx.x;        // 64 chunks x 256 px
    int t = threadIdx.x, w = t >> 6, l = t & 63, l15 = l & 15, lq = l >> 4;

    __shared__ __align__(16) unsigned short bfr[4][4][2][512];  // [pt][ks][hi/lo][lane*8]

    bf8 Ah[2][4], Al[2][4];
    #pragma unroll
    for (int r = 0; r < 2; ++r)
      #pragma unroll
      for (int ks = 0; ks < 4; ++ks) {
        size_t idx = (((size_t)b * 8 + (2*w + r)) * 4 + ks) * 64 + l;
        Ah[r][ks] = ((const bf8*)ahp)[idx];
        Al[r][ks] = ((const bf8*)alp)[idx];
      }
    float cbl[2][4];
    #pragma unroll
    for (int r = 0; r < 2; ++r)
      #pragma unroll
      for (int j = 0; j < 4; ++j)
        cbl[r][j] = wsf[OFF_CB + b*128 + (2*w + r)*16 + lq*4 + j];

    int pbase = chunk * 256;
    const float* cb0 = cond + (size_t)b * 128 * NN + pbase + w*16 + l15;

    float v[4][8];
    #pragma unroll
    for (int ks = 0; ks < 4; ++ks)
      #pragma unroll
      for (int j = 0; j < 8; ++j)
        v[ks][j] = cb0[(size_t)(ks*32 + lq*8 + j) * NN];

    for (int tile = 0; tile < 4; ++tile) {
        if (tile > 0) __syncthreads();
        #pragma unroll
        for (int ks = 0; ks < 4; ++ks) {
            union { unsigned u[4]; bf8 s; } uh, ul;
            #pragma unroll
            for (int q = 0; q < 4; ++q) {
                unsigned hp = cvtpk_bf16(v[ks][2*q], v[ks][2*q+1]);
                uh.u[q] = hp;
                float f0 = __builtin_bit_cast(float, hp << 16);
                float f1 = __builtin_bit_cast(float, hp & 0xFFFF0000u);
                ul.u[q] = cvtpk_bf16(v[ks][2*q] - f0, v[ks][2*q+1] - f1);
            }
            *(bf8*)&bfr[w][ks][0][l * 8] = uh.s;
            *(bf8*)&bfr[w][ks][1][l * 8] = ul.s;
        }
        __syncthreads();
        if (tile < 3) {
            const float* cp = cb0 + (tile + 1) * 64;
            #pragma unroll
            for (int ks = 0; ks < 4; ++ks)
              #pragma unroll
              for (int j = 0; j < 8; ++j)
                v[ks][j] = cp[(size_t)(ks*32 + lq*8 + j) * NN];
        }
        int tp = pbase + tile * 64;
        f4 acc[2][4];
        #pragma unroll
        for (int r = 0; r < 2; ++r)
          #pragma unroll
          for (int pt = 0; pt < 4; ++pt) acc[r][pt] = (f4){0,0,0,0};
        #pragma unroll
        for (int pt = 0; pt < 4; ++pt) {
            #pragma unroll
            for (int ks = 0; ks < 4; ++ks) {
                bf8 bh = *(const bf8*)&bfr[pt][ks][0][l * 8];
                bf8 bl = *(const bf8*)&bfr[pt][ks][1][l * 8];
                #pragma unroll
                for (int r = 0; r < 2; ++r) {
                    acc[r][pt] = MFMA16(Ah[r][ks], bh, acc[r][pt]);
                    acc[r][pt] = MFMA16(Al[r][ks], bh, acc[r][pt]);
                    acc[r][pt] = MFMA16(Ah[r][ks], bl, acc[r][pt]);
                }
            }
        }
        #pragma unroll
        for (int r = 0; r < 2; ++r)
          #pragma unroll
          for (int pt = 0; pt < 4; ++pt)
            #pragma unroll
            for (int j = 0; j < 4; ++j) {
                int o = (2*w + r)*16 + lq*4 + j;
                int p = tp + pt*16 + l15;
                y[((size_t)b*128 + o)*NN + p] = acc[r][pt][j] + cbl[r][j];
            }
    }
}

extern "C" void kernel_launch(void* const* d_in, const int* in_sizes, int n_in,
                              void* d_out, int out_size, void* d_ws, size_t ws_size,
                              hipStream_t stream) {
    const float* x        = (const float*)d_in[0];
    const float* cond     = (const float*)d_in[1];
    const float* gn_scale = (const float*)d_in[2];
    const float* gn_bias  = (const float*)d_in[3];
    const float* kv_w     = (const float*)d_in[4];
    const float* kv_b     = (const float*)d_in[5];
    const float* q_w      = (const float*)d_in[6];
    const float* q_b      = (const float*)d_in[7];
    const float* out_w    = (const float*)d_in[8];
    const float* out_b    = (const float*)d_in[9];
    float* y   = (float*)d_out;
    float* wsf = (float*)d_ws;

    unsigned short* WH = (unsigned short*)(wsf + OFF_WH);
    unsigned short* AH = (unsigned short*)(wsf + OFF_AH);
    unsigned short* AL = (unsigned short*)(wsf + OFF_AL);
    float* part = wsf + OFF_PART;

    bool big = ws_size >= (size_t)(OFF_XT + 16777216) * sizeof(float);

    unsigned short* XT;
    if (big) {
        XT = (unsigned short*)(wsf + OFF_XT);
    } else {
        XT = (unsigned short*)y;           // consumed by k3 before k6 writes y
    }

    k1a_fused<<<dim3(128, BATCH), 256, 0, stream>>>(x, XT, part);
    k1b_stats<<<BATCH, 256, 0, stream>>>(part, wsf);
    k2_weff<<<dim3(8, BATCH), 256, 0, stream>>>(kv_w, kv_b, gn_scale, gn_bias, wsf, WH);
    k3_attn<<<dim3(64, BATCH), 256, 0, stream>>>(XT, WH, wsf, part);
    k4_reduce<<<dim3(4, BATCH), 256, 0, stream>>>(part, wsf, 64);
    k5_buildA<<<dim3(8, BATCH), 256, 0, stream>>>(out_w, q_w, q_b, out_b, wsf, AH, AL);
    k6_mfma<<<dim3(64, BATCH), 256, 0, stream>>>(cond, AH, AL, wsf, y);
}

// Round 16
// 189.510 us; speedup vs baseline: 1.1329x; 1.0309x over previous
//
#include <hip/hip_runtime.h>
#include <hip/hip_bf16.h>
#include <cstddef>

#define BATCH 16
#define CC 128
#define NN 16384
#define GROUPS 32
#define EPSV 1e-5f

// workspace float offsets
#define OFF_MU    0          // 512
#define OFF_RSTD  512        // 512
#define OFF_BEFF  1024       // 4096
#define OFF_CTX   5120       // 65536
#define OFF_CB    70656      // 2048
#define OFF_WH    334848     // 524288 ushorts (W_eff hi frags)
#define OFF_AH    596992     // 131072 fl (A_b hi frags)
#define OFF_AL    728064     // 131072 fl (A_b lo frags)
#define OFF_PART  859136     // 1024*4224 fl = 4325376
#define OFF_XT    5184512    // xt hi-only: 16*16384*128 shorts = 16777216 fl
#define PART_STRIDE 4224

typedef __attribute__((ext_vector_type(8))) short bf8;
typedef __attribute__((ext_vector_type(4))) float f4;
#define MFMA16(a,b,c) __builtin_amdgcn_mfma_f32_16x16x32_bf16(a,b,c,0,0,0)

__device__ inline unsigned short bf16_rtn(float f) {
    unsigned u = __builtin_bit_cast(unsigned, f);
    unsigned r = (u + 0x7FFFu + ((u >> 16) & 1u)) >> 16;
    return (unsigned short)r;
}
__device__ inline float bf16_f(unsigned short h) {
    unsigned u = ((unsigned)h) << 16;
    return __builtin_bit_cast(float, u);
}
// HW packed f32->bf16 (RNE); dst[15:0]=bf16(a), dst[31:16]=bf16(b)
__device__ inline unsigned cvtpk_bf16(float a, float b) {
    unsigned r;
    asm("v_cvt_pk_bf16_f32 %0, %1, %2" : "=v"(r) : "v"(a), "v"(b));
    return r;
}

// ---------------- K1a: transpose to [px][c] bf16-hi + fused GN partial stats ----------------
__global__ __launch_bounds__(256) void k1a_fused(const float* __restrict__ src,
        unsigned short* __restrict__ xt, float* __restrict__ gp) {
    int b = blockIdx.y; int p0 = blockIdx.x * 128; int t = threadIdx.x;
    __shared__ unsigned short lh[128 * 136];
    int p = t & 127, chalf = t >> 7;
    const float* sp = src + (size_t)b * CC * NN + p0 + p;
    #pragma unroll 8
    for (int i = 0; i < 64; ++i) {
        int c = i * 2 + chalf;
        float v = sp[(size_t)c * NN];
        lh[p * 136 + c] = bf16_rtn(v);
    }
    __syncthreads();
    // fused stats from bf16(x): thread covers group g = t>>3, 16 px x 4 ch
    {
        int g = t >> 3, i8 = t & 7;
        float s = 0.f, sq = 0.f;
        for (int pp = i8 * 16; pp < i8 * 16 + 16; ++pp) {
            #pragma unroll
            for (int cc = 0; cc < 4; ++cc) {
                float v = bf16_f(lh[pp * 136 + g * 4 + cc]);
                s += v; sq += v * v;
            }
        }
        __shared__ float rs[256], rq[256];
        rs[t] = s; rq[t] = sq;
        __syncthreads();
        if (t < 32) {
            float a = 0.f, bq = 0.f;
            #pragma unroll
            for (int k = 0; k < 8; ++k) { a += rs[t * 8 + k]; bq += rq[t * 8 + k]; }
            float* d = gp + ((size_t)(b * 128 + blockIdx.x) * 32 + t) * 2;
            d[0] = a; d[1] = bq;
        }
    }
    // transpose write (hi only)
    int pr = t >> 4, c8 = (t & 15) * 8;
    #pragma unroll
    for (int j = 0; j < 8; ++j) {
        int p2 = j * 16 + pr;
        bf8 vh = *(const bf8*)&lh[p2 * 136 + c8];
        *(bf8*)&xt[((size_t)b * NN + p0 + p2) * 128 + c8] = vh;
    }
}

// ---------------- K1b: reduce group partials -> mu/rstd ----------------
__global__ void k1b_stats(const float* __restrict__ gp, float* __restrict__ wsf) {
    int b = blockIdx.x; int t = threadIdx.x;
    int g = t & 31, sl = t >> 5;
    float s = 0.f, sq = 0.f;
    for (int j = sl; j < 128; j += 8) {
        const float* p = gp + ((size_t)(b * 128 + j) * 32 + g) * 2;
        s += p[0]; sq += p[1];
    }
    __shared__ float rs[256], rq[256];
    rs[t] = s; rq[t] = sq; __syncthreads();
    if (t < 32) {
        #pragma unroll
        for (int k = 1; k < 8; ++k) { s += rs[t + 32 * k]; sq += rq[t + 32 * k]; }
        float mean = s * (1.f / 65536.f);
        float var  = sq * (1.f / 65536.f) - mean * mean;
        wsf[OFF_MU + b * 32 + t]   = mean;
        wsf[OFF_RSTD + b * 32 + t] = rsqrtf(var + EPSV);
    }
}

// ---------------- K2 v2: effective kv weights, coalesced via LDS (128 blocks) ----------------
__global__ __launch_bounds__(256) void k2_weff(const float* __restrict__ kv_w,
                        const float* __restrict__ kv_b,
                        const float* __restrict__ gn_scale, const float* __restrict__ gn_bias,
                        float* __restrict__ wsf, unsigned short* __restrict__ wh) {
    int b = blockIdx.y;
    int o0 = blockIdx.x * 32;           // 8 o-chunks x 32 outputs
    int t = threadIdx.x;
    __shared__ float wrow[32 * 128];    // 16 KB, kv_w rows o0..o0+32
    __shared__ float scl[128], sbm[128];// gamma*rstd ; gn_bias - mu*gamma*rstd
    __shared__ float bred[32][8];
    {   // coalesced stage: 4096 floats
        const float4* src = (const float4*)(kv_w + (size_t)o0 * 128);
        float4* dst = (float4*)wrow;
        #pragma unroll
        for (int i = 0; i < 4; ++i) dst[i * 256 + t] = src[i * 256 + t];
        if (t < 128) {
            int g = t >> 2;
            float r = wsf[OFF_RSTD + b * 32 + g];
            float m = wsf[OFF_MU + b * 32 + g];
            float sc = gn_scale[t] * r;
            scl[t] = sc;
            sbm[t] = gn_bias[t] - m * sc;
        }
    }
    __syncthreads();
    int ol = t >> 3;                    // 0..31
    int o  = o0 + ol;
    int q  = t & 7;                     // 2 frags: f = 2q, 2q+1
    // bias partial over c in [q*16, q*16+16)
    {
        float bacc = 0.f;
        const float* wr = &wrow[ol * 128 + q * 16];
        #pragma unroll
        for (int c = 0; c < 16; ++c) bacc += wr[c] * sbm[q * 16 + c];
        bred[ol][q] = bacc;
    }
    // pack 2 frags
    int h  = (o & 127) >> 5;
    int ct = ((o >> 4) & 1) + ((o >= 128) ? 2 : 0);
    #pragma unroll
    for (int f2 = 0; f2 < 2; ++f2) {
        int f = 2 * q + f2;
        int ks = f >> 2, eq = f & 3;
        int c0 = ks * 32 + eq * 8;
        bf8 pk;
        #pragma unroll
        for (int e = 0; e < 8; ++e)
            pk[e] = (short)bf16_rtn(wrow[ol * 128 + c0 + e] * scl[c0 + e]);
        int lane = (o & 15) + 16 * eq;
        size_t fo = ((((size_t)b * 4 + h) * 4 + ct) * 4 + ks) * 512 + (size_t)lane * 8;
        *(bf8*)&wh[fo] = pk;
    }
    __syncthreads();
    if (q == 0) {
        float bacc = 0.f;
        #pragma unroll
        for (int k = 0; k < 8; ++k) bacc += bred[ol][k];
        wsf[OFF_BEFF + b * 256 + o] = kv_b[o] + bacc;
    }
}

// ---------------- K3: MFMA kv-proj + streaming softmax-attention ----------------
// 2-ptgroup register prefetch pipeline (r13 proven-best config)
__global__ __launch_bounds__(256) void k3_attn(
    const unsigned short* __restrict__ xt,
    const unsigned short* __restrict__ wh, const float* __restrict__ wsf,
    float* __restrict__ part)
{
    int b = blockIdx.y, chunk = blockIdx.x;        // 64 chunks x 256 px
    int t = threadIdx.x, h = t >> 6, l = t & 63;
    int l15 = l & 15, lq = l >> 4;

    __shared__ unsigned short lds[4][2][32 * 64];  // [wave][ek|v][32 rows][64 px]

    bf8 W[4][4];                                    // [ct][ks], hi only
    #pragma unroll
    for (int ct = 0; ct < 4; ++ct)
      #pragma unroll
      for (int ks = 0; ks < 4; ++ks)
        W[ct][ks] = ((const bf8*)wh)[((((size_t)b*4 + h)*4 + ct)*4 + ks)*64 + l];

    float bk[4];
    #pragma unroll
    for (int ct = 0; ct < 4; ++ct) {
        int o = (ct < 2) ? (32*h + 16*ct + l15) : (128 + 32*h + 16*(ct-2) + l15);
        bk[ct] = wsf[OFF_BEFF + b * 256 + o];
    }

    bf8 ones;
    #pragma unroll
    for (int j = 0; j < 8; ++j) ones[j] = (short)0x3F80;

    f4 ctx[2][2]; f4 zac[2];
    #pragma unroll
    for (int i = 0; i < 2; ++i) {
        zac[i] = (f4){0,0,0,0};
        #pragma unroll
        for (int j = 0; j < 2; ++j) ctx[i][j] = (f4){0,0,0,0};
    }

    int pbase = chunk * 256;
    const unsigned short* xbase = xt + ((size_t)b * NN + pbase + l15) * 128 + lq * 8;
    #define FRAG(fp, ks) (*(const bf8*)(xbase + (size_t)(fp) * 2048 + (ks) * 32))

    bf8 pre[2][4];
    #pragma unroll
    for (int i = 0; i < 2; ++i)
      #pragma unroll
      for (int ks = 0; ks < 4; ++ks) pre[i][ks] = FRAG(i, ks);

    for (int tile = 0; tile < 4; ++tile) {
        #pragma unroll
        for (int half = 0; half < 2; ++half) {
            int nfp = tile * 4 + half * 2 + 2;
            int cfp = (nfp < 16) ? nfp : 0;
            bf8 nxt[2][4];
            #pragma unroll
            for (int i = 0; i < 2; ++i)
              #pragma unroll
              for (int ks = 0; ks < 4; ++ks) nxt[i][ks] = FRAG(cfp + i, ks);
            #pragma unroll
            for (int i = 0; i < 2; ++i) {
                int pt = half * 2 + i;
                f4 a4[4];
                #pragma unroll
                for (int ct = 0; ct < 4; ++ct) a4[ct] = (f4){0,0,0,0};
                #pragma unroll
                for (int ks = 0; ks < 4; ++ks) {
                    #pragma unroll
                    for (int ct = 0; ct < 4; ++ct)
                        a4[ct] = MFMA16(pre[i][ks], W[ct][ks], a4[ct]);
                }
                int p = pt * 16 + lq * 4;          // 4 consecutive px
                #pragma unroll
                for (int ct = 0; ct < 4; ++ct) {
                    int row = (ct & 1) * 16 + l15;
                    int sel = ct >> 1;             // 0 = EK, 1 = V
                    float v0 = a4[ct][0] + bk[ct];
                    float v1 = a4[ct][1] + bk[ct];
                    float v2 = a4[ct][2] + bk[ct];
                    float v3 = a4[ct][3] + bk[ct];
                    if (sel == 0) {
                        v0 = __expf(v0); v1 = __expf(v1);
                        v2 = __expf(v2); v3 = __expf(v3);
                    }
                    unsigned lo32 = cvtpk_bf16(v0, v1);
                    unsigned hi32 = cvtpk_bf16(v2, v3);
                    unsigned byte = ((unsigned)(row * 128 + p * 2)) ^ (((unsigned)(row & 7)) << 4);
                    *(uint2*)((char*)&lds[h][sel][0] + byte) = make_uint2(lo32, hi32);
                }
            }
            #pragma unroll
            for (int i = 0; i < 2; ++i)
              #pragma unroll
              for (int ks = 0; ks < 4; ++ks) pre[i][ks] = nxt[i][ks];
        }
        // PV + Z (wave-local; compiler inserts lgkmcnt)
        #pragma unroll
        for (int ks2 = 0; ks2 < 2; ++ks2) {
            int p8 = ks2 * 32 + lq * 8;
            bf8 ek[2], vv[2];
            #pragma unroll
            for (int dt = 0; dt < 2; ++dt) {
                int row = dt * 16 + l15;
                unsigned byte = ((unsigned)(row * 128 + p8 * 2)) ^ (((unsigned)(row & 7)) << 4);
                ek[dt] = *(const bf8*)((char*)&lds[h][0][0] + byte);
                vv[dt] = *(const bf8*)((char*)&lds[h][1][0] + byte);
            }
            #pragma unroll
            for (int dt = 0; dt < 2; ++dt) {
                #pragma unroll
                for (int et = 0; et < 2; ++et)
                    ctx[dt][et] = MFMA16(ek[dt], vv[et], ctx[dt][et]);
                zac[dt] = MFMA16(ek[dt], ones, zac[dt]);
            }
        }
    }
    #undef FRAG
    // partial write
    float* pb = part + (size_t)(b * 64 + chunk) * PART_STRIDE;
    #pragma unroll
    for (int dt = 0; dt < 2; ++dt) {
        #pragma unroll
        for (int et = 0; et < 2; ++et)
            #pragma unroll
            for (int j = 0; j < 4; ++j) {
                int d = 32*h + dt*16 + lq*4 + j;
                int e = et*16 + l15;
                pb[d * 32 + e] = ctx[dt][et][j];
            }
        if (l15 == 0)
            #pragma unroll
            for (int j = 0; j < 4; ++j)
                pb[4096 + 32*h + dt*16 + lq*4 + j] = zac[dt][j];
    }
}

// ---------------- K4: reduce partials -> context = S/Z ----------------
__global__ __launch_bounds__(256) void k4_reduce(const float* __restrict__ part,
                                                 float* __restrict__ wsf, int nbpb) {
    int q = blockIdx.x, b = blockIdx.y;
    int tid = threadIdx.x;
    int hdl = tid >> 3;                 // 0..31
    int hd = q * 32 + hdl;
    int e0 = (tid & 7) * 4;
    float s[4] = {0.f, 0.f, 0.f, 0.f};
    float z = 0.f;
    for (int i = 0; i < nbpb; ++i) {
        const float* pb = part + (size_t)(b * nbpb + i) * PART_STRIDE;
        float4 v = *(const float4*)&pb[hd * 32 + e0];
        s[0] += v.x; s[1] += v.y; s[2] += v.z; s[3] += v.w;
        if ((tid & 7) == 0) z += pb[4096 + hd];
    }
    __shared__ float zs[32];
    if ((tid & 7) == 0) zs[hdl] = z;
    __syncthreads();
    float zi = 1.f / zs[hdl];
    float* cg = wsf + OFF_CTX + (size_t)b * 4096;
    #pragma unroll
    for (int j = 0; j < 4; ++j) cg[hd * 32 + e0 + j] = s[j] * zi;
}

// ---------------- K5: A_b = out_w . blockdiag(ctx^T) . q_w ; c_b ; frag-pack ----------------
__global__ __launch_bounds__(256) void k5_buildA(const float* __restrict__ out_w,
                          const float* __restrict__ q_w,
                          const float* __restrict__ q_b, const float* __restrict__ out_b,
                          float* __restrict__ wsf,
                          unsigned short* __restrict__ ahp, unsigned short* __restrict__ alp) {
    int b = blockIdx.y;
    int oh = blockIdx.x * 16;           // 8 o-chunks of 16 rows
    int tid = threadIdx.x;
    __shared__ float ctx_p[128 * 33];
    __shared__ float T_s[16 * 132];
    {
        const float* src = wsf + OFF_CTX + (size_t)b * 4096;
        for (int i = tid; i < 4096; i += 256)
            ctx_p[(i >> 5) * 33 + (i & 31)] = src[i];
    }
    __syncthreads();
    int ol = tid >> 4;                  // 0..15
    int o = oh + ol;
    int jb = tid & 15;                  // 0..15
    int j0 = jb * 8;
    int h = j0 >> 5;
    {
        float ow[32];
        #pragma unroll
        for (int e4 = 0; e4 < 8; ++e4) {
            float4 v = *(const float4*)&out_w[o * 128 + h * 32 + e4 * 4];
            ow[e4*4+0]=v.x; ow[e4*4+1]=v.y; ow[e4*4+2]=v.z; ow[e4*4+3]=v.w;
        }
        #pragma unroll
        for (int dd = 0; dd < 8; ++dd) {
            int r = h * 32 + (j0 & 31) + dd;
            const float* cp = &ctx_p[r * 33];
            float a0 = 0.f, a1 = 0.f, a2 = 0.f, a3 = 0.f;
            #pragma unroll
            for (int e = 0; e < 32; e += 4) {
                a0 += ow[e+0] * cp[e+0];
                a1 += ow[e+1] * cp[e+1];
                a2 += ow[e+2] * cp[e+2];
                a3 += ow[e+3] * cp[e+3];
            }
            T_s[ol * 132 + j0 + dd] = (a0 + a1) + (a2 + a3);
        }
    }
    __syncthreads();
    {
        int ci0 = jb * 8;
        float a[8];
        #pragma unroll
        for (int i = 0; i < 8; ++i) a[i] = 0.f;
        for (int j = 0; j < 128; ++j) {
            float tv = T_s[ol * 132 + j];
            float4 v0 = *(const float4*)&q_w[j * 128 + ci0];
            float4 v1 = *(const float4*)&q_w[j * 128 + ci0 + 4];
            a[0] += tv*v0.x; a[1] += tv*v0.y; a[2] += tv*v0.z; a[3] += tv*v0.w;
            a[4] += tv*v1.x; a[5] += tv*v1.y; a[6] += tv*v1.z; a[7] += tv*v1.w;
        }
        int ks = ci0 >> 5;
        int eq = (ci0 >> 3) & 3;
        int lane = (o & 15) + 16 * eq;
        bf8 ph, pl;
        #pragma unroll
        for (int e = 0; e < 8; ++e) {
            unsigned short hh = bf16_rtn(a[e]);
            ph[e] = (short)hh;
            pl[e] = (short)bf16_rtn(a[e] - bf16_f(hh));
        }
        size_t fo = ((((size_t)b * 8 + (o >> 4)) * 4 + ks) * 64 + lane) * 8;
        *(bf8*)&ahp[fo] = ph;
        *(bf8*)&alp[fo] = pl;
        if (jb == 0) {
            float cb = 0.f;
            for (int j = 0; j < 128; ++j) cb += T_s[ol * 132 + j] * q_b[j];
            wsf[OFF_CB + b * 128 + o] = cb + out_b[o];
        }
    }
}

// ---------------- K6 (MFMA): y = A_b . cond + c_b ----------------
// producer/consumer + T14 async-stage + double-buffered LDS (1 barrier/tile)
__global__ __launch_bounds__(256) void k6_mfma(
    const float* __restrict__ cond,
    const unsigned short* __restrict__ ahp, const unsigned short* __restrict__ alp,
    const float* __restrict__ wsf, float* __restrict__ y)
{
    int b = blockIdx.y, chunk = blockIdx.x;        // 64 chunks x 256 px
    int t = threadIdx.x, w = t >> 6, l = t & 63, l15 = l & 15, lq = l >> 4;

    __shared__ __align__(16) unsigned short bfr[2][4][4][2][512]; // [buf][pt][ks][hi/lo][lane*8]

    bf8 Ah[2][4], Al[2][4];
    #pragma unroll
    for (int r = 0; r < 2; ++r)
      #pragma unroll
      for (int ks = 0; ks < 4; ++ks) {
        size_t idx = (((size_t)b * 8 + (2*w + r)) * 4 + ks) * 64 + l;
        Ah[r][ks] = ((const bf8*)ahp)[idx];
        Al[r][ks] = ((const bf8*)alp)[idx];
      }
    float cbl[2][4];
    #pragma unroll
    for (int r = 0; r < 2; ++r)
      #pragma unroll
      for (int j = 0; j < 4; ++j)
        cbl[r][j] = wsf[OFF_CB + b*128 + (2*w + r)*16 + lq*4 + j];

    int pbase = chunk * 256;
    const float* cb0 = cond + (size_t)b * 128 * NN + pbase + w*16 + l15;

    // staging registers, live across the loop
    float v[4][8];
    #pragma unroll
    for (int ks = 0; ks < 4; ++ks)
      #pragma unroll
      for (int j = 0; j < 8; ++j)
        v[ks][j] = cb0[(size_t)(ks*32 + lq*8 + j) * NN];

    for (int tile = 0; tile < 4; ++tile) {
        int cur = tile & 1;
        // convert current staging regs -> LDS buf[cur]
        // (safe without a pre-barrier: buf[cur] readers finished before the
        //  previous tile's barrier — per-wave order conv(t) < bar(t) < mfma(t))
        #pragma unroll
        for (int ks = 0; ks < 4; ++ks) {
            union { unsigned u[4]; bf8 s; } uh, ul;
            #pragma unroll
            for (int q = 0; q < 4; ++q) {
                unsigned hp = cvtpk_bf16(v[ks][2*q], v[ks][2*q+1]);
                uh.u[q] = hp;
                float f0 = __builtin_bit_cast(float, hp << 16);
                float f1 = __builtin_bit_cast(float, hp & 0xFFFF0000u);
                ul.u[q] = cvtpk_bf16(v[ks][2*q] - f0, v[ks][2*q+1] - f1);
            }
            *(bf8*)&bfr[cur][w][ks][0][l * 8] = uh.s;
            *(bf8*)&bfr[cur][w][ks][1][l * 8] = ul.s;
        }
        __syncthreads();
        // issue next tile's loads now — they fly under the MFMA phase
        if (tile < 3) {
            const float* cp = cb0 + (tile + 1) * 64;
            #pragma unroll
            for (int ks = 0; ks < 4; ++ks)
              #pragma unroll
              for (int j = 0; j < 8; ++j)
                v[ks][j] = cp[(size_t)(ks*32 + lq*8 + j) * NN];
        }
        // consumer: all waves, all pt
        int tp = pbase + tile * 64;
        f4 acc[2][4];
        #pragma unroll
        for (int r = 0; r < 2; ++r)
          #pragma unroll
          for (int pt = 0; pt < 4; ++pt) acc[r][pt] = (f4){0,0,0,0};
        #pragma unroll
        for (int pt = 0; pt < 4; ++pt) {
            #pragma unroll
            for (int ks = 0; ks < 4; ++ks) {
                bf8 bh = *(const bf8*)&bfr[cur][pt][ks][0][l * 8];
                bf8 bl = *(const bf8*)&bfr[cur][pt][ks][1][l * 8];
                #pragma unroll
                for (int r = 0; r < 2; ++r) {
                    acc[r][pt] = MFMA16(Ah[r][ks], bh, acc[r][pt]);
                    acc[r][pt] = MFMA16(Al[r][ks], bh, acc[r][pt]);
                    acc[r][pt] = MFMA16(Ah[r][ks], bl, acc[r][pt]);
                }
            }
        }
        #pragma unroll
        for (int r = 0; r < 2; ++r)
          #pragma unroll
          for (int pt = 0; pt < 4; ++pt)
            #pragma unroll
            for (int j = 0; j < 4; ++j) {
                int o = (2*w + r)*16 + lq*4 + j;
                int p = tp + pt*16 + l15;
                y[((size_t)b*128 + o)*NN + p] = acc[r][pt][j] + cbl[r][j];
            }
    }
}

extern "C" void kernel_launch(void* const* d_in, const int* in_sizes, int n_in,
                              void* d_out, int out_size, void* d_ws, size_t ws_size,
                              hipStream_t stream) {
    const float* x        = (const float*)d_in[0];
    const float* cond     = (const float*)d_in[1];
    const float* gn_scale = (const float*)d_in[2];
    const float* gn_bias  = (const float*)d_in[3];
    const float* kv_w     = (const float*)d_in[4];
    const float* kv_b     = (const float*)d_in[5];
    const float* q_w      = (const float*)d_in[6];
    const float* q_b      = (const float*)d_in[7];
    const float* out_w    = (const float*)d_in[8];
    const float* out_b    = (const float*)d_in[9];
    float* y   = (float*)d_out;
    float* wsf = (float*)d_ws;

    unsigned short* WH = (unsigned short*)(wsf + OFF_WH);
    unsigned short* AH = (unsigned short*)(wsf + OFF_AH);
    unsigned short* AL = (unsigned short*)(wsf + OFF_AL);
    float* part = wsf + OFF_PART;

    bool big = ws_size >= (size_t)(OFF_XT + 16777216) * sizeof(float);

    unsigned short* XT;
    if (big) {
        XT = (unsigned short*)(wsf + OFF_XT);
    } else {
        XT = (unsigned short*)y;           // consumed by k3 before k6 writes y
    }

    k1a_fused<<<dim3(128, BATCH), 256, 0, stream>>>(x, XT, part);
    k1b_stats<<<BATCH, 256, 0, stream>>>(part, wsf);
    k2_weff<<<dim3(8, BATCH), 256, 0, stream>>>(kv_w, kv_b, gn_scale, gn_bias, wsf, WH);
    k3_attn<<<dim3(64, BATCH), 256, 0, stream>>>(XT, WH, wsf, part);
    k4_reduce<<<dim3(4, BATCH), 256, 0, stream>>>(part, wsf, 64);
    k5_buildA<<<dim3(8, BATCH), 256, 0, stream>>>(out_w, q_w, q_b, out_b, wsf, AH, AL);
    k6_mfma<<<dim3(64, BATCH), 256, 0, stream>>>(cond, AH, AL, wsf, y);
}